// Round 8
// baseline (21.415 us; speedup 1.0000x reference)
//
#include <hip/hip_runtime.h>
#include <math.h>

#define DIMS 512
#define BATCH 1024
#define CLS 256
#define ROWS (BATCH + CLS)   // 1280 stacked rows: [f_norm; w_norm]

#define EPS_PD 1e-6f
#define DEPS2 (512.0f * 1e-6f * 1e-6f)   // D * eps^2
#define EPS_NORM 1e-12f

typedef short bf16x8 __attribute__((ext_vector_type(8)));   // 8 bf16 = 4 VGPRs
typedef float f32x4 __attribute__((ext_vector_type(4)));

__device__ __forceinline__ float waveReduceSum(float v) {
#pragma unroll
  for (int off = 32; off > 0; off >>= 1)
    v += __shfl_xor(v, off, 64);
  return v;
}

// round-to-nearest-even float -> bf16
__device__ __forceinline__ unsigned short f2bf(float x) {
  unsigned int u = __float_as_uint(x);
  u += 0x7fffu + ((u >> 16) & 1u);
  return (unsigned short)(u >> 16);
}

// K1: grid = 320 x 256 threads (4 waves, one row per wave).
// Row r<1024 -> feat, else weight row r-1024. Normalize row, cast to bf16
// into fnw[r][512]; Srow[r] = sum of normalized components.
__global__ __launch_bounds__(256) void k_norm(
    const float* __restrict__ feat, const float* __restrict__ wt,
    unsigned short* __restrict__ fnw, float* __restrict__ Srow) {
  const int r = blockIdx.x * 4 + (threadIdx.x >> 6);
  const int lane = threadIdx.x & 63;
  const float* src = (r < BATCH) ? (feat + (size_t)r * DIMS)
                                 : (wt + (size_t)(r - BATCH) * DIMS);
  const float4* s4 = (const float4*)src;

  float4 a = s4[lane];        // d = lane*4 .. +3
  float4 c = s4[lane + 64];   // d = 256 + lane*4 .. +3

  float ss = a.x*a.x + a.y*a.y + a.z*a.z + a.w*a.w
           + c.x*c.x + c.y*c.y + c.z*c.z + c.w*c.w;
  float sm = a.x + a.y + a.z + a.w + c.x + c.y + c.z + c.w;
  ss = waveReduceSum(ss);
  sm = waveReduceSum(sm);
  const float rn = 1.f / fmaxf(sqrtf(ss), EPS_NORM);

  ushort4 pa, pc;
  pa.x = f2bf(a.x * rn); pa.y = f2bf(a.y * rn);
  pa.z = f2bf(a.z * rn); pa.w = f2bf(a.w * rn);
  pc.x = f2bf(c.x * rn); pc.y = f2bf(c.y * rn);
  pc.z = f2bf(c.z * rn); pc.w = f2bf(c.w * rn);

  ushort4* dst = (ushort4*)(fnw + (size_t)r * DIMS);
  dst[lane] = pa;
  dst[lane + 64] = pc;

  if (lane == 0) Srow[r] = sm * rn;
}

// K2: protoc Gram via MFMA + fused dist-sum. grid = (8,8) 32x32 tiles over
// the 256x256 w-Gram; block = 64 (one wave). Each wave computes its tile's
// dists (exact diagonal), wave-reduces, writes ONE partial (no atomics, no
// init needed -> deterministic).
__global__ __launch_bounds__(64) void k_protoc(
    const unsigned short* __restrict__ fnw, const float* __restrict__ Srow,
    float* __restrict__ partial) {
  const int lane = threadIdx.x;
  const int i0 = blockIdx.y * 32;          // protoc rows (w index)
  const int j0 = blockIdx.x * 32;          // protoc cols (w index)

  const int lm = lane & 15;
  const int lk = (lane >> 4) * 8;

  const unsigned short* arow0 = fnw + (size_t)(BATCH + i0 + lm) * DIMS + lk;
  const unsigned short* arow1 = fnw + (size_t)(BATCH + i0 + 16 + lm) * DIMS + lk;
  const unsigned short* brow0 = fnw + (size_t)(BATCH + j0 + lm) * DIMS + lk;
  const unsigned short* brow1 = fnw + (size_t)(BATCH + j0 + 16 + lm) * DIMS + lk;

  f32x4 acc00 = {0.f,0.f,0.f,0.f}, acc01 = {0.f,0.f,0.f,0.f};
  f32x4 acc10 = {0.f,0.f,0.f,0.f}, acc11 = {0.f,0.f,0.f,0.f};

#pragma unroll
  for (int k0 = 0; k0 < DIMS; k0 += 32) {
    const bf16x8 a0 = *(const bf16x8*)(arow0 + k0);
    const bf16x8 a1 = *(const bf16x8*)(arow1 + k0);
    const bf16x8 b0 = *(const bf16x8*)(brow0 + k0);
    const bf16x8 b1 = *(const bf16x8*)(brow1 + k0);
    acc00 = __builtin_amdgcn_mfma_f32_16x16x32_bf16(a0, b0, acc00, 0, 0, 0);
    acc01 = __builtin_amdgcn_mfma_f32_16x16x32_bf16(a0, b1, acc01, 0, 0, 0);
    acc10 = __builtin_amdgcn_mfma_f32_16x16x32_bf16(a1, b0, acc10, 0, 0, 0);
    acc11 = __builtin_amdgcn_mfma_f32_16x16x32_bf16(a1, b1, acc11, 0, 0, 0);
  }

  const int crow = (lane >> 4) * 4;        // C/D layout: col=lane&15, row=crow+q
  const int ccol = lane & 15;

  const float swj0 = Srow[BATCH + j0 + ccol];
  const float swj1 = Srow[BATCH + j0 + 16 + ccol];

  float s = 0.f;
  const f32x4 accs[4] = {acc00, acc01, acc10, acc11};
#pragma unroll
  for (int hi = 0; hi < 2; ++hi) {
#pragma unroll
    for (int q = 0; q < 4; ++q) {
      const int i = i0 + hi * 16 + crow + q;
      const float swi = Srow[BATCH + i];
#pragma unroll
      for (int hj = 0; hj < 2; ++hj) {
        const int j = j0 + hj * 16 + ccol;
        const float dot = accs[hi * 2 + hj][q];
        const float swj = hj ? swj1 : swj0;
        float dist;
        if (i == j) {
          dist = sqrtf(DEPS2);             // exact self-distance
        } else {
          const float d2 = 2.f - 2.f * dot + 2.f * EPS_PD * (swi - swj) + DEPS2;
          dist = sqrtf(fmaxf(d2, 0.f));
        }
        s += dist;
      }
    }
  }

  s = waveReduceSum(s);
  if (lane == 0) partial[blockIdx.y * 8 + blockIdx.x] = s;
}

// K3: main GEMM feat_norm[1024x512] . w_norm^T + fully fused epilogue.
// grid = (32,8) 32x32 tiles; block = 64 (one wave). Sums the 64 protoc
// partials in-wave (one extra waveReduce), computes dist/logits/scale and
// stores out directly from the MFMA accumulators. No dots buffer.
__global__ __launch_bounds__(64) void k_main(
    const unsigned short* __restrict__ fnw, const float* __restrict__ Srow,
    const float* __restrict__ partial, const float* __restrict__ dscale,
    const int* __restrict__ use_ds, float* __restrict__ out) {
  const int lane = threadIdx.x;
  const int r0 = blockIdx.x * 32;          // feature rows
  const int j0 = blockIdx.y * 32;          // classes

  // start the partial-sum load early; reduce after the MFMA loop
  const float myPartial = partial[lane];   // exactly 64 entries

  const int lm = lane & 15;
  const int lk = (lane >> 4) * 8;

  const unsigned short* arow0 = fnw + (size_t)(r0 + lm) * DIMS + lk;
  const unsigned short* arow1 = fnw + (size_t)(r0 + 16 + lm) * DIMS + lk;
  const unsigned short* brow0 = fnw + (size_t)(BATCH + j0 + lm) * DIMS + lk;
  const unsigned short* brow1 = fnw + (size_t)(BATCH + j0 + 16 + lm) * DIMS + lk;

  f32x4 acc00 = {0.f,0.f,0.f,0.f}, acc01 = {0.f,0.f,0.f,0.f};
  f32x4 acc10 = {0.f,0.f,0.f,0.f}, acc11 = {0.f,0.f,0.f,0.f};

#pragma unroll
  for (int k0 = 0; k0 < DIMS; k0 += 32) {
    const bf16x8 a0 = *(const bf16x8*)(arow0 + k0);
    const bf16x8 a1 = *(const bf16x8*)(arow1 + k0);
    const bf16x8 b0 = *(const bf16x8*)(brow0 + k0);
    const bf16x8 b1 = *(const bf16x8*)(brow1 + k0);
    acc00 = __builtin_amdgcn_mfma_f32_16x16x32_bf16(a0, b0, acc00, 0, 0, 0);
    acc01 = __builtin_amdgcn_mfma_f32_16x16x32_bf16(a0, b1, acc01, 0, 0, 0);
    acc10 = __builtin_amdgcn_mfma_f32_16x16x32_bf16(a1, b0, acc10, 0, 0, 0);
    acc11 = __builtin_amdgcn_mfma_f32_16x16x32_bf16(a1, b1, acc11, 0, 0, 0);
  }

  const float S = waveReduceSum(myPartial);
  const float Ssc = 0.1f * S;
  const float sc = (use_ds[0] != 0) ? fabsf(dscale[0]) : 1.0f;

  const int crow = (lane >> 4) * 4;
  const int ccol = lane & 15;

  const float swj0 = Srow[BATCH + j0 + ccol];
  const float swj1 = Srow[BATCH + j0 + 16 + ccol];

  const f32x4 accs[4] = {acc00, acc01, acc10, acc11};
#pragma unroll
  for (int hi = 0; hi < 2; ++hi) {
#pragma unroll
    for (int q = 0; q < 4; ++q) {
      const int i = r0 + hi * 16 + crow + q;
      const float sfi = Srow[i];
#pragma unroll
      for (int hj = 0; hj < 2; ++hj) {
        const int j = j0 + hj * 16 + ccol;
        const float dot = accs[hi * 2 + hj][q];
        const float swj = hj ? swj1 : swj0;
        const float d2 = 2.f - 2.f * dot + 2.f * EPS_PD * (sfi - swj) + DEPS2;
        const float dist = sqrtf(fmaxf(d2, 0.f));
        out[(size_t)i * CLS + j] = (Ssc - dist) * sc;
      }
    }
  }
}

extern "C" void kernel_launch(void* const* d_in, const int* in_sizes, int n_in,
                              void* d_out, int out_size, void* d_ws, size_t ws_size,
                              hipStream_t stream) {
  const float* feat = (const float*)d_in[0];     // [1024,512]
  const float* wt   = (const float*)d_in[1];     // [256,512]
  const float* ds   = (const float*)d_in[2];     // [1]
  const int*   use  = (const int*)d_in[3];       // scalar
  float* out = (float*)d_out;                    // [1024,256] fp32

  // ws layout: fnw bf16 1280*512*2 = 1,310,720 B ; then floats
  unsigned short* fnw = (unsigned short*)d_ws;
  float* fbase   = (float*)((char*)d_ws + (size_t)ROWS * DIMS * 2);
  float* Srow    = fbase;                        // 1280
  float* partial = fbase + ROWS;                 // 64

  k_norm<<<ROWS / 4, 256, 0, stream>>>(feat, wt, fnw, Srow);
  k_protoc<<<dim3(8, 8), 64, 0, stream>>>(fnw, Srow, partial);
  k_main<<<dim3(32, 8), 64, 0, stream>>>(fnw, Srow, partial, ds, use, out);
}